// Round 1
// 580.335 us; speedup vs baseline: 1.2233x; 1.2233x over previous
//
#include <hip/hip_runtime.h>

#define IN_CH 128
#define OUT_CH 128
#define LDSPAD 136   // padded row stride (elements); 16B-aligned fragment reads, 2-way
                     // bank aliasing only (free per m136)

typedef short bf16x8 __attribute__((ext_vector_type(8)));
typedef float f32x4  __attribute__((ext_vector_type(4)));

__device__ __forceinline__ unsigned short f32_to_bf16_bits(float f) {
    unsigned u = __builtin_bit_cast(unsigned, f);
    u += 0x7FFFu + ((u >> 16) & 1u);   // RNE; finite values only in this pipeline
    return (unsigned short)(u >> 16);
}
__device__ __forceinline__ float bf16_bits_to_f32(unsigned short b) {
    return __builtin_bit_cast(float, (unsigned)b << 16);
}

// ---------------------------------------------------------------------------
// Kernel 0: runtime dtype detection (1 block). flags[0]=X fp32, flags[1]=W1 fp32,
// flags[2]=W2 fp32, flags[3]=idx int64
// ---------------------------------------------------------------------------
__global__ void detect_kernel(const unsigned short* __restrict__ X,
                              const unsigned short* __restrict__ W1,
                              const unsigned short* __restrict__ W2,
                              const int* __restrict__ idx,
                              int* __restrict__ flags) {
    __shared__ int red[4];
    const int t = threadIdx.x;
    if (t < 4) red[t] = 0;
    __syncthreads();
    #pragma unroll
    for (int w = 0; w < 3; ++w) {
        const unsigned short* p = (w == 0) ? X : (w == 1) ? W1 : W2;
        int crazy = 0;
        for (int j = t; j < 512; j += 256) {
            const unsigned short h = p[j];
            const int e = (h >> 7) & 0xFF;
            const int man = h & 0x7F;
            // insane as bf16 for this data: |v| >= 2^17, or denormal
            if (e >= 0x90 || (e == 0 && man != 0)) crazy++;
        }
        if (crazy) atomicAdd(&red[w], crazy);
    }
    {   // idx: odd int32 words are int64 high-words (all 0 since values < 10000)
        if (idx[2 * t + 1] != 0) atomicAdd(&red[3], 1);
    }
    __syncthreads();
    if (t == 0) {
        flags[0] = red[0] > 16 ? 1 : 0;
        flags[1] = red[1] > 16 ? 1 : 0;
        flags[2] = red[2] > 16 ? 1 : 0;
        flags[3] = red[3] < 8  ? 1 : 0;
    }
}

// ---------------------------------------------------------------------------
// Kernel 1: per-segment counts (idx-width adaptive)
// ---------------------------------------------------------------------------
__global__ void count_kernel(const int* __restrict__ idx, int* __restrict__ cnt,
                             const int* __restrict__ flags, int n) {
    const int sh = flags[3];
    int i = blockIdx.x * blockDim.x + threadIdx.x;
    if (i < n) atomicAdd(&cnt[idx[(size_t)i << sh]], 1);
}

// ---------------------------------------------------------------------------
// Kernel 2: exclusive scan of counts -> off[] (start offsets) and cur[]
// (mutable cursors for the permutation build). Single block, 1024 threads.
// ---------------------------------------------------------------------------
__global__ void scan_kernel(const int* __restrict__ cnt, int* __restrict__ off,
                            int* __restrict__ cur, int dim) {
    __shared__ int wtot[16];
    __shared__ int woff[16];
    __shared__ int carry_s;
    const int tid = threadIdx.x;
    const int wv = tid >> 6, ln = tid & 63;
    if (tid == 0) carry_s = 0;
    __syncthreads();
    for (int base = 0; base < dim; base += 1024) {
        const int i = base + tid;
        const int orig = (i < dim) ? cnt[i] : 0;
        int v = orig;
        #pragma unroll
        for (int d = 1; d < 64; d <<= 1) {
            int w = __shfl_up(v, d, 64);
            if (ln >= d) v += w;
        }
        if (ln == 63) wtot[wv] = v;
        __syncthreads();
        if (tid == 0) {
            int acc = carry_s;
            #pragma unroll
            for (int k = 0; k < 16; ++k) { woff[k] = acc; acc += wtot[k]; }
            carry_s = acc;
        }
        __syncthreads();
        const int excl = woff[wv] + v - orig;
        if (i < dim) { off[i] = excl; cur[i] = excl; }
        __syncthreads();
    }
}

// ---------------------------------------------------------------------------
// Kernel 3: build row permutation grouped by segment
// ---------------------------------------------------------------------------
__global__ void perm_kernel(const int* __restrict__ idx, int* __restrict__ cur,
                            int* __restrict__ perm, const int* __restrict__ flags,
                            int n) {
    const int sh = flags[3];
    int i = blockIdx.x * blockDim.x + threadIdx.x;
    if (i < n) {
        const int s = idx[(size_t)i << sh];
        const int p = atomicAdd(&cur[s], 1);
        perm[p] = i;
    }
}

// ---------------------------------------------------------------------------
// Kernel 4: fused MLP (2x Linear+ReLU via MFMA) with per-segment in-register
// row reduction and a single coalesced store per output row. NO fp32 atomics.
// Block = 256 threads = 4 waves; each block owns whole segments (grid-stride);
// per segment, rows are consumed 16 at a time via perm[]; wave w owns output
// channels [32w,32w+32) as two 16x16 n-tiles.
// ---------------------------------------------------------------------------
__global__ __launch_bounds__(256)
void mlp_gather_kernel(const unsigned short* __restrict__ X,
                       const int* __restrict__ perm,
                       const int* __restrict__ off,
                       const int* __restrict__ cnt,
                       const unsigned short* __restrict__ W1,
                       const unsigned short* __restrict__ B1,
                       const unsigned short* __restrict__ W2,
                       const unsigned short* __restrict__ B2,
                       float* __restrict__ out,
                       const int* __restrict__ flags,
                       int dim)
{
    __shared__ short lds_x[16 * LDSPAD];
    __shared__ short lds_h[16 * LDSPAD];

    const int xf32  = flags[0];
    const int w1f32 = flags[1];
    const int w2f32 = flags[2];

    const int tid  = threadIdx.x;
    const int wave = tid >> 6;
    const int lane = tid & 63;
    const int m    = lane & 15;   // A row / B col / D col
    const int quad = lane >> 4;

    // Preload this wave's W1/W2 B-fragments (B[k][n]=W[n][k] -> 8 contiguous k
    // from row n of row-major W) and biases.
    bf16x8 w1f[2][4], w2f[2][4];
    float  b1c[2], b2c[2];
    #pragma unroll
    for (int t = 0; t < 2; ++t) {
        const int n = wave * 32 + t * 16 + m;
        b1c[t] = w1f32 ? ((const float*)B1)[n] : bf16_bits_to_f32(B1[n]);
        b2c[t] = w2f32 ? ((const float*)B2)[n] : bf16_bits_to_f32(B2[n]);
        #pragma unroll
        for (int kc = 0; kc < 4; ++kc) {
            const int ko = kc * 32 + quad * 8;
            if (w1f32) {
                const float* Wf = (const float*)W1;
                f32x4 lo = *(const f32x4*)(Wf + n * IN_CH + ko);
                f32x4 hi = *(const f32x4*)(Wf + n * IN_CH + ko + 4);
                bf16x8 v;
                #pragma unroll
                for (int j = 0; j < 4; ++j) {
                    v[j]     = (short)f32_to_bf16_bits(lo[j]);
                    v[4 + j] = (short)f32_to_bf16_bits(hi[j]);
                }
                w1f[t][kc] = v;
            } else {
                w1f[t][kc] = *(const bf16x8*)(W1 + n * IN_CH + ko);
            }
            if (w2f32) {
                const float* Wf = (const float*)W2;
                f32x4 lo = *(const f32x4*)(Wf + n * OUT_CH + ko);
                f32x4 hi = *(const f32x4*)(Wf + n * OUT_CH + ko + 4);
                bf16x8 v;
                #pragma unroll
                for (int j = 0; j < 4; ++j) {
                    v[j]     = (short)f32_to_bf16_bits(lo[j]);
                    v[4 + j] = (short)f32_to_bf16_bits(hi[j]);
                }
                w2f[t][kc] = v;
            } else {
                w2f[t][kc] = *(const bf16x8*)(W2 + n * OUT_CH + ko);
            }
        }
    }

    const int srow = tid >> 4;   // staging: 16 threads/row
    const int sseg = tid & 15;

    for (int s = blockIdx.x; s < dim; s += gridDim.x) {
        const int c     = cnt[s];
        const int start = off[s];
        float sum0 = 0.f, sum1 = 0.f;

        for (int base = 0; base < c; base += 16) {
            // ---- stage 16 gathered X rows into padded LDS (dtype-adaptive) ----
            {
                const int gr = base + srow;
                bf16x8 v = {0, 0, 0, 0, 0, 0, 0, 0};
                if (gr < c) {
                    const int row = perm[start + gr];
                    if (xf32) {
                        const float* Xf = (const float*)X;
                        f32x4 lo = *(const f32x4*)(Xf + (size_t)row * IN_CH + sseg * 8);
                        f32x4 hi = *(const f32x4*)(Xf + (size_t)row * IN_CH + sseg * 8 + 4);
                        #pragma unroll
                        for (int j = 0; j < 4; ++j) {
                            v[j]     = (short)f32_to_bf16_bits(lo[j]);
                            v[4 + j] = (short)f32_to_bf16_bits(hi[j]);
                        }
                    } else {
                        v = *(const bf16x8*)(X + (size_t)row * IN_CH + sseg * 8);
                    }
                }
                *(bf16x8*)&lds_x[srow * LDSPAD + sseg * 8] = v;
            }
            __syncthreads();

            // ---- layer 1 ----
            f32x4 acc0 = {0.f, 0.f, 0.f, 0.f}, acc1 = {0.f, 0.f, 0.f, 0.f};
            #pragma unroll
            for (int kc = 0; kc < 4; ++kc) {
                bf16x8 a = *(const bf16x8*)&lds_x[m * LDSPAD + kc * 32 + quad * 8];
                acc0 = __builtin_amdgcn_mfma_f32_16x16x32_bf16(a, w1f[0][kc], acc0, 0, 0, 0);
                acc1 = __builtin_amdgcn_mfma_f32_16x16x32_bf16(a, w1f[1][kc], acc1, 0, 0, 0);
            }
            // relu+bias; D (col=lane&15,row=quad*4+reg) -> lds_h[src_row][channel]
            #pragma unroll
            for (int t = 0; t < 2; ++t) {
                const int col = wave * 32 + t * 16 + m;
                const float bias = b1c[t];
                const f32x4 acc = t == 0 ? acc0 : acc1;
                #pragma unroll
                for (int r = 0; r < 4; ++r) {
                    float v = acc[r] + bias;
                    v = v > 0.f ? v : 0.f;
                    lds_h[(quad * 4 + r) * LDSPAD + col] = (short)f32_to_bf16_bits(v);
                }
            }
            __syncthreads();

            // ---- layer 2 ----
            f32x4 acc2_0 = {0.f, 0.f, 0.f, 0.f}, acc2_1 = {0.f, 0.f, 0.f, 0.f};
            #pragma unroll
            for (int kc = 0; kc < 4; ++kc) {
                bf16x8 a = *(const bf16x8*)&lds_h[m * LDSPAD + kc * 32 + quad * 8];
                acc2_0 = __builtin_amdgcn_mfma_f32_16x16x32_bf16(a, w2f[0][kc], acc2_0, 0, 0, 0);
                acc2_1 = __builtin_amdgcn_mfma_f32_16x16x32_bf16(a, w2f[1][kc], acc2_1, 0, 0, 0);
            }

            // ---- relu+bias per row, masked in-lane row reduction ----
            // ReLU must happen per row BEFORE summing; rows live in distinct
            // (quad, reg) slots, so cross-chunk MFMA accumulation is invalid.
            #pragma unroll
            for (int t = 0; t < 2; ++t) {
                const float bias = b2c[t];
                const f32x4 acc = t == 0 ? acc2_0 : acc2_1;
                float sr = 0.f;
                #pragma unroll
                for (int r = 0; r < 4; ++r) {
                    if (base + quad * 4 + r < c) {
                        float v = acc[r] + bias;
                        sr += (v > 0.f ? v : 0.f);
                    }
                }
                if (t == 0) sum0 += sr; else sum1 += sr;
            }
            // (no barrier needed here: next stage writes lds_x, guarded by the
            //  post-stage barrier; lds_h rewrite is guarded by the same barrier)
        }

        // ---- cross-quad reduction (rows 0..15) + single store, pre-divided ----
        sum0 += __shfl_xor(sum0, 16, 64);
        sum0 += __shfl_xor(sum0, 32, 64);
        sum1 += __shfl_xor(sum1, 16, 64);
        sum1 += __shfl_xor(sum1, 32, 64);
        if (quad == 0) {
            const float inv = 1.f / (float)(c > 1 ? c : 1);
            float* o = out + (size_t)s * OUT_CH + wave * 32 + m;
            o[0]  = sum0 * inv;   // t = 0 channels
            o[16] = sum1 * inv;   // t = 1 channels
        }
    }
}

extern "C" void kernel_launch(void* const* d_in, const int* in_sizes, int n_in,
                              void* d_out, int out_size, void* d_ws, size_t ws_size,
                              hipStream_t stream) {
    // size-based input resolution (proven equivalent to ordered mapping in R3)
    int iX = 0;
    for (int i = 1; i < n_in; ++i)
        if (in_sizes[i] > in_sizes[iX]) iX = i;
    const int n_src = in_sizes[iX] / IN_CH;
    int iI = -1, iW1 = -1, iW2 = -1, iB1 = -1, iB2 = -1;
    for (int i = 0; i < n_in; ++i) {
        if (i == iX) continue;
        const int s = in_sizes[i];
        if (s == n_src && iI < 0) iI = i;
        else if (s == IN_CH * OUT_CH) { if (iW1 < 0) iW1 = i; else if (iW2 < 0) iW2 = i; }
        else if (s == OUT_CH) { if (iB1 < 0) iB1 = i; else if (iB2 < 0) iB2 = i; }
    }

    const unsigned short* X  = (const unsigned short*)d_in[iX];
    const int*            ix = (const int*)d_in[iI];
    const unsigned short* W1 = (const unsigned short*)d_in[iW1];
    const unsigned short* B1 = (const unsigned short*)d_in[iB1];
    const unsigned short* W2 = (const unsigned short*)d_in[iW2];
    const unsigned short* B2 = (const unsigned short*)d_in[iB2];
    float* out = (float*)d_out;

    const int dim = out_size / OUT_CH;

    int* flags = (int*)d_ws;                       // [0,256) reserved
    int* cnt   = (int*)((char*)d_ws + 256);        // dim
    int* off   = cnt + dim;                        // dim
    int* cur   = off + dim;                        // dim
    int* perm  = cur + dim;                        // n_src

    hipMemsetAsync(cnt, 0, (size_t)dim * sizeof(int), stream);

    detect_kernel<<<1, 256, 0, stream>>>(X, W1, W2, ix, flags);

    count_kernel<<<(n_src + 255) / 256, 256, 0, stream>>>(ix, cnt, flags, n_src);

    scan_kernel<<<1, 1024, 0, stream>>>(cnt, off, cur, dim);

    perm_kernel<<<(n_src + 255) / 256, 256, 0, stream>>>(ix, cur, perm, flags, n_src);

    const int grid = dim < 2048 ? dim : 2048;
    mlp_gather_kernel<<<grid, 256, 0, stream>>>(X, perm, off, cnt, W1, B1, W2, B2,
                                                out, flags, dim);
}